// Round 9
// baseline (214.333 us; speedup 1.0000x reference)
//
#include <hip/hip_runtime.h>
#include <hip/hip_bf16.h>
#include <math.h>

typedef __bf16 bf16;
typedef __bf16 bf16x8 __attribute__((ext_vector_type(8)));
typedef __bf16 bf16x4 __attribute__((ext_vector_type(4)));
typedef float f32x4 __attribute__((ext_vector_type(4)));
typedef unsigned int u32;
typedef u32 u32x4 __attribute__((ext_vector_type(4)));

#define S_ 4096
#define D_ 1024
#define H_ 16
#define HD_ 64
#define N3_ 3072
#define NSPLIT 4

// async global->LDS 16B (m97 pattern)
typedef const __attribute__((address_space(1))) void* gas1_t;
typedef __attribute__((address_space(3))) void* las3_t;
static __device__ __forceinline__ void g2l16(const void* g, void* l) {
  __builtin_amdgcn_global_load_lds((gas1_t)g, (las3_t)l, 16, 0, 0);
}

static __device__ __forceinline__ u32 fbits(float x) {
  union { float f; u32 u; } c; c.f = x; return c.u;
}

// ---------------- fused prep: cvt x -> bf16, transpose both weights ----------------
__global__ __launch_bounds__(256) void prep_kernel(const float* __restrict__ x,
                                                   bf16* __restrict__ xb,
                                                   const float* __restrict__ w_qkv,
                                                   bf16* __restrict__ wqkvT,
                                                   const float* __restrict__ w_proj,
                                                   bf16* __restrict__ wprojT) {
  __shared__ float t[32][33];
  const int b = blockIdx.x;
  if (b < 4096) {
    int i = (b * 256 + threadIdx.x) * 4;
    float4 v = *(const float4*)(x + i);
    bf16x4 o;
    o.x = (bf16)v.x; o.y = (bf16)v.y; o.z = (bf16)v.z; o.w = (bf16)v.w;
    *(bf16x4*)(xb + i) = o;
    return;
  }
  const float* in; bf16* outp; int ldin, bx, by;
  if (b < 7168) { int b2 = b - 4096; in = w_qkv;  outp = wqkvT;  ldin = N3_; bx = (b2 % 96) * 32; by = (b2 / 96) * 32; }
  else          { int b3 = b - 7168; in = w_proj; outp = wprojT; ldin = D_;  bx = (b3 % 32) * 32; by = (b3 / 32) * 32; }
  const int tx = threadIdx.x & 31, ty = threadIdx.x >> 5;
#pragma unroll
  for (int i = 0; i < 4; ++i)
    t[ty + i * 8][tx] = in[(size_t)(by + ty + i * 8) * ldin + bx + tx];
  __syncthreads();
#pragma unroll
  for (int i = 0; i < 4; ++i)
    outp[(size_t)(bx + ty + i * 8) * D_ + by + tx] = (bf16)t[tx][ty + i * 8];
}

// ---------------- bf16 GEMM (m97 pattern): C = A * Bt^T + bias ----------------
template <int BN>
__global__ __launch_bounds__(256) void gemm_bt(const bf16* __restrict__ A,
                                               const bf16* __restrict__ Bt,
                                               const float* __restrict__ bias,
                                               bf16* __restrict__ outb,
                                               float* __restrict__ outf,
                                               bf16* __restrict__ vTout,
                                               int M, int N, int K,
                                               int qlim, float qscale) {
  constexpr int NT = BN / 32;  // n-tiles per wave
  __shared__ bf16 sA[128 * 32];
  __shared__ bf16 sB[BN * 32];
  const int tid = threadIdx.x;
  const int wave = tid >> 6, lane = tid & 63;
  const int col = lane & 15, quad = lane >> 4;
  const int wm = (wave & 1) * 64, wn = (wave >> 1) * (BN / 2);
  const long bm = (long)blockIdx.x * 128, bn = (long)blockIdx.y * BN;
  const int srow = tid >> 2;        // 0..63
  const int soff = (tid & 3) * 8;   // elem in 32-elem row

  f32x4 acc[4][NT] = {};

  for (int kb = 0; kb < K; kb += 32) {
    __syncthreads();
    g2l16(A + (bm + srow) * (long)K + kb + soff,      &sA[tid * 8]);
    g2l16(A + (bm + 64 + srow) * (long)K + kb + soff, &sA[2048 + tid * 8]);
#pragma unroll
    for (int i = 0; i < BN / 64; ++i)
      g2l16(Bt + (bn + i * 64 + srow) * (long)K + kb + soff, &sB[i * 2048 + tid * 8]);
    __syncthreads();

    bf16x8 af[4], bfr[NT];
#pragma unroll
    for (int t = 0; t < 4; ++t)
      af[t] = *(const bf16x8*)(&sA[(wm + t * 16 + col) * 32 + quad * 8]);
#pragma unroll
    for (int t = 0; t < NT; ++t)
      bfr[t] = *(const bf16x8*)(&sB[(wn + t * 16 + col) * 32 + quad * 8]);
#pragma unroll
    for (int mt = 0; mt < 4; ++mt)
#pragma unroll
      for (int nt = 0; nt < NT; ++nt)
        acc[mt][nt] = __builtin_amdgcn_mfma_f32_16x16x32_bf16(af[mt], bfr[nt], acc[mt][nt], 0, 0, 0);
  }

#pragma unroll
  for (int mt = 0; mt < 4; ++mt) {
#pragma unroll
    for (int nt = 0; nt < NT; ++nt) {
      long gn = bn + wn + nt * 16 + col;
      float bv = bias ? bias[gn] : 0.f;
      if (vTout && gn >= 2 * D_) {  // V column -> transposed store
        bf16x4 vv;
        long gm0 = bm + wm + mt * 16 + quad * 4;
#pragma unroll
        for (int i = 0; i < 4; ++i) vv[i] = (bf16)(acc[mt][nt][i] + bv);
        *(bf16x4*)(&vTout[(gn - 2 * D_) * (long)S_ + gm0]) = vv;
      } else {
        float sc = (gn < qlim) ? qscale : 1.0f;
#pragma unroll
        for (int i = 0; i < 4; ++i) {
          long gm = bm + wm + mt * 16 + quad * 4 + i;
          float v = (acc[mt][nt][i] + bv) * sc;
          if (outf) outf[gm * N + gn] = v;
          else      outb[gm * N + gn] = (bf16)v;
        }
      }
    }
  }
}

// ---------------- causal flash attention, 4-way exact K-split ----------------
// grid (H, 32, 4), block 256 = 4 waves; 128 q-rows/block; 64-key chunks,
// double-buffered XOR-swizzled LDS, register prefetch, ONE barrier per iter.
// R9: all 16 swizzled fragment offsets hoisted out of the loop (loop-invariant),
// P packed to bf16 via v_perm truncation (bias cancels: l uses the same
// truncated pfrag), staging pointers bumped instead of recomputed.
__device__ __forceinline__ int swz_g(int row) {
  return (row & 3) | ((((row >> 2) ^ (row >> 3)) & 1) << 2);
}

__global__ __launch_bounds__(256) void attn_kernel(const bf16* __restrict__ qkv,
                                                   const bf16* __restrict__ vT,
                                                   bf16* __restrict__ Opart,
                                                   float* __restrict__ lws) {
  __shared__ bf16 sK[2][64 * 64];
  __shared__ bf16 sV[2][64 * 64];
  const int hh = blockIdx.x;
  const int qb = (int)(gridDim.y - 1 - blockIdx.y);  // heavy blocks dispatch first
  const int sp = blockIdx.z;
  const int tid = threadIdx.x;
  const int wave = tid >> 6, lane = tid & 63;
  const int col = lane & 15, quad = lane >> 4;
  const int qbase = qb * 128 + wave * 32;

  // Q fragments (B-operand layout) for the two 16-row subtiles
  const bf16* qp0 = qkv + (size_t)(qbase + col) * N3_ + hh * HD_;
  bf16x8 aq[2][2];
  aq[0][0] = *(const bf16x8*)(qp0 + quad * 8);
  aq[0][1] = *(const bf16x8*)(qp0 + 32 + quad * 8);
  aq[1][0] = *(const bf16x8*)(qp0 + 16 * N3_ + quad * 8);
  aq[1][1] = *(const bf16x8*)(qp0 + 16 * N3_ + 32 + quad * 8);

  bf16x8 ones;
#pragma unroll
  for (int j = 0; j < 8; ++j) ones[j] = (bf16)1.0f;

  f32x4 acc[2][4] = {};
  f32x4 acc_l[2] = {};

  const int krow = (col >> 2) * 8 + (col & 3);  // permuted K row (m = col)
  const int niter = 2 * (qb + 1);
  const int base = niter >> 2, rem = niter & 3;
  const int it0 = sp * base + (sp < rem ? sp : rem);
  const int len = base + (sp < rem ? 1 : 0);
  const int it1 = it0 + len;

  // ---- hoisted fragment offsets (loop-invariant; elems into 4096-elem tile) ----
  int koff[4][2], voff[2][4];
#pragma unroll
  for (int t = 0; t < 4; ++t) {
    int row = (t >> 1) * 32 + (t & 1) * 4 + krow;
    int pc = quad ^ swz_g(row);
    koff[t][0] = row * 64 + pc * 8;
    koff[t][1] = row * 64 + (pc ^ 4) * 8;
  }
#pragma unroll
  for (int c = 0; c < 2; ++c)
#pragma unroll
    for (int n = 0; n < 4; ++n) {
      int row = n * 16 + col;
      voff[c][n] = row * 64 + (((4 * c + quad) ^ swz_g(row)) * 8);
    }

  // staging map: row = tid>>2 (0..63), two 16B chunks c0, c0+1
  const int srow = tid >> 2;
  const int sc0 = (tid & 3) * 2;
  const int gs = swz_g(srow);
  const int soff0 = srow * 64 + ((sc0 ^ gs) * 8);
  const int soff1 = srow * 64 + (((sc0 + 1) ^ gs) * 8);

  // staging source pointers (bumped each iter)
  const bf16* kgp = qkv + D_ + hh * HD_ + (size_t)(it0 * 64 + srow) * N3_ + sc0 * 8;
  const bf16* vgp = vT + (size_t)hh * HD_ * S_ + (size_t)srow * S_ + it0 * 64 + sc0 * 8;

  if (len > 0) {
    // prologue: stage chunk it0 into buf 0
    *(int4*)(&sK[0][soff0]) = *(const int4*)kgp;
    *(int4*)(&sK[0][soff1]) = *(const int4*)(kgp + 8);
    *(int4*)(&sV[0][soff0]) = *(const int4*)vgp;
    *(int4*)(&sV[0][soff1]) = *(const int4*)(vgp + 8);
    kgp += 64 * N3_;
    vgp += 64;
    __syncthreads();

    for (int j = it0; j < it1; ++j) {
      const int kb = j * 64;
      const int cur = (j - it0) & 1;
      const bool more = (j + 1 < it1);
      int4 pk0, pk1, pv0, pv1;
      if (more) {  // prefetch next chunk into regs (latency hidden by compute)
        pk0 = *(const int4*)kgp; pk1 = *(const int4*)(kgp + 8);
        pv0 = *(const int4*)vgp; pv1 = *(const int4*)(vgp + 8);
        kgp += 64 * N3_;
        vgp += 64;
      }

      if (kb < qbase + 32) {  // wave has unmasked work in this chunk
        const bool act0 = kb < qbase + 16;
        const bf16* kc = &sK[cur][0];
        const bf16* vc = &sV[cur][0];

        // --- S^T tiles: K-frags shared across subtiles ---
        f32x4 st[2][4];
#pragma unroll
        for (int t = 0; t < 4; ++t) {
          bf16x8 bk0 = *(const bf16x8*)(kc + koff[t][0]);
          bf16x8 bk1 = *(const bf16x8*)(kc + koff[t][1]);
          if (act0) {
            f32x4 z = {};
            z = __builtin_amdgcn_mfma_f32_16x16x32_bf16(bk0, aq[0][0], z, 0, 0, 0);
            st[0][t] = __builtin_amdgcn_mfma_f32_16x16x32_bf16(bk1, aq[0][1], z, 0, 0, 0);
          }
          f32x4 z = {};
          z = __builtin_amdgcn_mfma_f32_16x16x32_bf16(bk0, aq[1][0], z, 0, 0, 0);
          st[1][t] = __builtin_amdgcn_mfma_f32_16x16x32_bf16(bk1, aq[1][1], z, 0, 0, 0);
        }

        // --- p = exp2(s); causal mask only on diagonal chunks; perm-pack ---
        bf16x8 pfrag[2][2];
#pragma unroll
        for (int s2 = 0; s2 < 2; ++s2) {
          if (s2 == 0 && !act0) continue;
          const int rowbase = qbase + 16 * s2;
          float p[4][4];
          if (kb + 63 <= rowbase) {  // fully unmasked
#pragma unroll
            for (int t = 0; t < 4; ++t)
#pragma unroll
              for (int r = 0; r < 4; ++r)
                p[t][r] = __builtin_amdgcn_exp2f(st[s2][t][r]);
          } else {                   // diagonal: causal mask
#pragma unroll
            for (int t = 0; t < 4; ++t)
#pragma unroll
              for (int r = 0; r < 4; ++r) {
                int key = kb + (t >> 1) * 32 + quad * 8 + (t & 1) * 4 + r;
                p[t][r] = (key > rowbase + col)
                              ? 0.f
                              : __builtin_amdgcn_exp2f(st[s2][t][r]);
              }
          }
          // truncate-pack pairs of f32 -> bf16x2 via one v_perm each
#pragma unroll
          for (int c = 0; c < 2; ++c) {
            union { bf16x8 v; u32x4 u; } pu;
            pu.u[0] = __builtin_amdgcn_perm(fbits(p[2 * c][1]),     fbits(p[2 * c][0]),     0x07060302u);
            pu.u[1] = __builtin_amdgcn_perm(fbits(p[2 * c][3]),     fbits(p[2 * c][2]),     0x07060302u);
            pu.u[2] = __builtin_amdgcn_perm(fbits(p[2 * c + 1][1]), fbits(p[2 * c + 1][0]), 0x07060302u);
            pu.u[3] = __builtin_amdgcn_perm(fbits(p[2 * c + 1][3]), fbits(p[2 * c + 1][2]), 0x07060302u);
            pfrag[s2][c] = pu.v;
          }
        }

        // --- PV + l-accumulation: V-frags shared across subtiles ---
#pragma unroll
        for (int c = 0; c < 2; ++c) {
#pragma unroll
          for (int n = 0; n < 4; ++n) {
            bf16x8 bv = *(const bf16x8*)(vc + voff[c][n]);
            if (act0)
              acc[0][n] = __builtin_amdgcn_mfma_f32_16x16x32_bf16(pfrag[0][c], bv, acc[0][n], 0, 0, 0);
            acc[1][n] = __builtin_amdgcn_mfma_f32_16x16x32_bf16(pfrag[1][c], bv, acc[1][n], 0, 0, 0);
          }
          if (act0)
            acc_l[0] = __builtin_amdgcn_mfma_f32_16x16x32_bf16(pfrag[0][c], ones, acc_l[0], 0, 0, 0);
          acc_l[1] = __builtin_amdgcn_mfma_f32_16x16x32_bf16(pfrag[1][c], ones, acc_l[1], 0, 0, 0);
        }
      }

      if (more) {  // write prefetched chunk into the other buffer
        bf16* kn = &sK[cur ^ 1][0];
        bf16* vn = &sV[cur ^ 1][0];
        *(int4*)(kn + soff0) = pk0;
        *(int4*)(kn + soff1) = pk1;
        *(int4*)(vn + soff0) = pv0;
        *(int4*)(vn + soff1) = pv1;
      }
      __syncthreads();
    }
  }

  // --- epilogue: write unnormalized O partial (bf16) and l partial (f32) ---
  bf16* Op = Opart + (size_t)sp * S_ * D_;
#pragma unroll
  for (int s2 = 0; s2 < 2; ++s2) {
    const int rowbase = qbase + 16 * s2;
    if (col == 0) {
#pragma unroll
      for (int r = 0; r < 4; ++r)
        lws[((size_t)sp * H_ + hh) * S_ + rowbase + quad * 4 + r] = acc_l[s2][r];
    }
#pragma unroll
    for (int n = 0; n < 4; ++n)
#pragma unroll
      for (int r = 0; r < 4; ++r)
        Op[(size_t)(rowbase + quad * 4 + r) * D_ + hh * HD_ + n * 16 + col] =
            (bf16)acc[s2][n][r];
  }
}

// ---------------- combine the four K-split partials ----------------
__global__ __launch_bounds__(256) void attn_combine(const bf16* __restrict__ Opart,
                                                    const float* __restrict__ lws,
                                                    bf16* __restrict__ outb) {
  int e = (blockIdx.x * 256 + threadIdx.x) * 8;
  int s = e >> 10;              // / D_
  int h = (e & (D_ - 1)) >> 6;  // head
  float l = 0.f;
#pragma unroll
  for (int sp = 0; sp < NSPLIT; ++sp) l += lws[((size_t)sp * H_ + h) * S_ + s];
  float inv = 1.0f / l;
  float o[8] = {};
#pragma unroll
  for (int sp = 0; sp < NSPLIT; ++sp) {
    bf16x8 a = *(const bf16x8*)(Opart + (size_t)sp * S_ * D_ + e);
#pragma unroll
    for (int j = 0; j < 8; ++j) o[j] += (float)a[j];
  }
  bf16x8 r;
#pragma unroll
  for (int j = 0; j < 8; ++j) r[j] = (bf16)(o[j] * inv);
  *(bf16x8*)(outb + e) = r;
}

// ---------------- host orchestration ----------------
extern "C" void kernel_launch(void* const* d_in, const int* in_sizes, int n_in,
                              void* d_out, int out_size, void* d_ws, size_t ws_size,
                              hipStream_t stream) {
  const float* x      = (const float*)d_in[0];
  const float* w_qkv  = (const float*)d_in[1];
  const float* b_qkv  = (const float*)d_in[2];
  const float* w_proj = (const float*)d_in[3];
  const float* b_proj = (const float*)d_in[4];
  float* out = (float*)d_out;

  bf16* xb     = (bf16*)d_ws;                       // [4096][1024]    8 MB (reused as attn)
  bf16* wqkvT  = xb + (size_t)S_ * D_;              // [3072][1024]    6 MB
  bf16* wprojT = wqkvT + (size_t)N3_ * D_;          // [1024][1024]    2 MB
  bf16* qkv    = wprojT + (size_t)D_ * D_;          // [4096][3072]   24 MB (V cols unused)
  bf16* vT     = qkv + (size_t)S_ * N3_;            // [1024][4096]    8 MB
  bf16* Opart  = vT + (size_t)D_ * S_;              // [4][4096][1024] 32 MB
  float* lws   = (float*)(Opart + (size_t)NSPLIT * S_ * D_);  // [4][16][4096] 1 MB
  bf16* attn   = xb;  // xb is dead after the QKV GEMM

  const float QSCALE = 0.125f * 1.44269504088896f;  // 1/sqrt(64) * log2(e)

  prep_kernel<<<dim3(8192), 256, 0, stream>>>(x, xb, w_qkv, wqkvT, w_proj, wprojT);
  // QKV GEMM; Q columns pre-scaled; V columns written transposed to vT
  gemm_bt<128><<<dim3(S_ / 128, N3_ / 128), 256, 0, stream>>>(
      xb, wqkvT, b_qkv, qkv, nullptr, vT, S_, N3_, D_, D_, QSCALE);
  attn_kernel<<<dim3(H_, S_ / 128, NSPLIT), 256, 0, stream>>>(qkv, vT, Opart, lws);
  attn_combine<<<dim3((S_ * D_) / 2048), 256, 0, stream>>>(Opart, lws, attn);
  // proj GEMM: 128x64 tiles -> 512 blocks (2/CU) for latency hiding
  gemm_bt<64><<<dim3(S_ / 128, D_ / 64), 256, 0, stream>>>(
      attn, wprojT, b_proj, nullptr, out, nullptr, S_, D_, D_, 0, 1.0f);
}